// Round 6
// baseline (32.278 us; speedup 1.0000x reference)
//
#include <hip/hip_runtime.h>
#include <math.h>

#define TPB 1024
#define NDIM 8

typedef float fvec4 __attribute__((ext_vector_type(4)));
typedef float fvec2 __attribute__((ext_vector_type(2)));

__global__ __launch_bounds__(TPB) void vegas_map_kernel(
    const float* __restrict__ u,      // [n, 8]
    const float* __restrict__ grid,   // [8, gcols]
    float* __restrict__ x_out,        // [n, 8]
    float* __restrict__ lj_out,       // [n]
    int n, int gcols, float lj_const) // lj_const = 8 * ln(ninc)
{
    extern __shared__ float lds_grid[];   // 8 * gcols floats (32 KB for gcols=1001)
    const int ninc = gcols - 1;
    const int gtot4 = (NDIM * gcols) >> 2;

    // Stage grid table into LDS with 16B loads (coalesced, conflict-free).
    const fvec4* __restrict__ g4 = (const fvec4*)grid;
    fvec4* lds4 = (fvec4*)lds_grid;
    for (int t = threadIdx.x; t < gtot4; t += TPB)
        lds4[t] = g4[t];
    __syncthreads();

    const float fninc = (float)ninc;
    const fvec4* __restrict__ u4 = (const fvec4*)u;
    fvec4* __restrict__ x4 = (fvec4*)x_out;
    fvec2* __restrict__ lj2 = (fvec2*)lj_out;

    const int m = n >> 1;                 // point pairs; thread owns points 2j, 2j+1
    const int stride = gridDim.x * TPB;

    for (int j = blockIdx.x * TPB + threadIdx.x; j < m; j += stride) {
        // Issue all 4 u-loads up front: 64 B contiguous per lane -> 2x MLP.
        fvec4 a0 = u4[4 * j];
        fvec4 b0 = u4[4 * j + 1];
        fvec4 a1 = u4[4 * j + 2];
        fvec4 b1 = u4[4 * j + 3];

        fvec2 lj;
        #pragma unroll
        for (int pt = 0; pt < 2; ++pt) {
            fvec4 a = pt ? a1 : a0;
            fvec4 b = pt ? b1 : b0;
            float uv[NDIM] = {a.x, a.y, a.z, a.w, b.x, b.y, b.z, b.w};
            float xv[NDIM];
            float prod = 1.0f;

            #pragma unroll
            for (int d = 0; d < NDIM; ++d) {
                float un  = uv[d] * fninc;
                int   iu  = (int)un;                 // trunc == floor (un >= 0)
                int   iuc = iu < ninc ? iu : (ninc - 1);
                float du  = un - (float)iuc;         // clamp trick: edge reproduces upper
                const float* row = lds_grid + d * gcols;
                float g0 = row[iuc];
                float g1 = row[iuc + 1];             // adjacent -> ds_read2_b32 pair
                float h  = g1 - g0;                  // == inc[d][iuc] bit-exactly
                xv[d] = g0 + h * du;
                prod *= h;                           // ninc factor hoisted into lj_const
            }

            fvec4 oa = {xv[0], xv[1], xv[2], xv[3]};
            fvec4 ob = {xv[4], xv[5], xv[6], xv[7]};
            x4[4 * j + 2 * pt]     = oa;             // 64 B contiguous per lane total
            x4[4 * j + 2 * pt + 1] = ob;
            lj[pt] = __logf(prod) + lj_const;        // sum(log) == log(prod) + 8*ln(ninc)
        }
        lj2[j] = lj;                                 // single 8 B coalesced store
    }

    // Odd-n tail (not hit for n = 2M, kept for generality).
    if ((n & 1) && blockIdx.x == 0 && threadIdx.x == 0) {
        const int p = n - 1;
        fvec4 a = u4[2 * p];
        fvec4 b = u4[2 * p + 1];
        float uv[NDIM] = {a.x, a.y, a.z, a.w, b.x, b.y, b.z, b.w};
        float xv[NDIM];
        float prod = 1.0f;
        #pragma unroll
        for (int d = 0; d < NDIM; ++d) {
            float un  = uv[d] * fninc;
            int   iu  = (int)un;
            int   iuc = iu < ninc ? iu : (ninc - 1);
            float du  = un - (float)iuc;
            const float* row = lds_grid + d * gcols;
            float g0 = row[iuc];
            float g1 = row[iuc + 1];
            float h  = g1 - g0;
            xv[d] = g0 + h * du;
            prod *= h;
        }
        fvec4 oa = {xv[0], xv[1], xv[2], xv[3]};
        fvec4 ob = {xv[4], xv[5], xv[6], xv[7]};
        x4[2 * p]     = oa;
        x4[2 * p + 1] = ob;
        lj_out[p] = __logf(prod) + lj_const;
    }
}

extern "C" void kernel_launch(void* const* d_in, const int* in_sizes, int n_in,
                              void* d_out, int out_size, void* d_ws, size_t ws_size,
                              hipStream_t stream) {
    const float* u    = (const float*)d_in[0];   // [N, 8]
    const float* grid = (const float*)d_in[1];   // [8, ninc+1]
    // d_in[2] = inc (recomputed as adjacent grid diffs), d_in[3] = ninc (derived)
    const int n     = in_sizes[0] / NDIM;
    const int gcols = in_sizes[1] / NDIM;        // ninc + 1
    const int ninc  = gcols - 1;

    float* x_out  = (float*)d_out;
    float* lj_out = (float*)d_out + (size_t)n * NDIM;

    const float lj_const = (float)(NDIM * log((double)ninc));

    int pairs = n >> 1;
    int blocks = (pairs + TPB - 1) / TPB;
    if (blocks > 512) blocks = 512;              // 2 blocks/CU x 256 CUs = 32 waves/CU
    size_t lds_bytes = (size_t)NDIM * gcols * sizeof(float);

    vegas_map_kernel<<<blocks, TPB, lds_bytes, stream>>>(u, grid, x_out, lj_out,
                                                         n, gcols, lj_const);
}

// Round 7
// 26.918 us; speedup vs baseline: 1.1991x; 1.1991x over previous
//
#include <hip/hip_runtime.h>
#include <math.h>

#define TPB 1024
#define NDIM 8

typedef float fvec4 __attribute__((ext_vector_type(4)));

__global__ __launch_bounds__(TPB) void vegas_map_kernel(
    const float* __restrict__ u,      // [n, 8] = [nent] float4 entries
    const float* __restrict__ grid,   // [8, gcols]
    float* __restrict__ x_out,        // [n, 8]
    float* __restrict__ lj_out,       // [n]
    int nent, int gcols, float lj_const) // nent = 2*n; lj_const = 8*ln(ninc)
{
    extern __shared__ float lds_grid[];   // 8 * gcols floats (32 KB for gcols=1001)
    const int ninc = gcols - 1;
    const int gtot4 = (NDIM * gcols) >> 2;

    // Stage grid table into LDS (coalesced 16B loads).
    const fvec4* __restrict__ g4 = (const fvec4*)grid;
    fvec4* lds4 = (fvec4*)lds_grid;
    for (int t = threadIdx.x; t < gtot4; t += TPB)
        lds4[t] = g4[t];
    __syncthreads();

    const float fninc = (float)ninc;
    const fvec4* __restrict__ u4 = (const fvec4*)u;
    fvec4* __restrict__ x4 = (fvec4*)x_out;

    // Lane owns ONE float4 entry = 4 dims of one point. All strides are
    // multiples of 64 lanes -> entry parity == lane parity, so the dim-block
    // (0-3 vs 4-7) and its LDS row base are loop-invariant per thread.
    const float* rows = lds_grid + (threadIdx.x & 1) * (4 * gcols);
    const bool is_even = ((threadIdx.x & 1) == 0);

    const int stride = gridDim.x * TPB;
    for (int e = blockIdx.x * TPB + threadIdx.x; e < nent; e += stride) {
        fvec4 a = u4[e];                  // perfectly coalesced: 16B/lane contiguous
        float uv[4] = {a.x, a.y, a.z, a.w};
        float xv[4];
        float pp = 1.0f;

        #pragma unroll
        for (int k = 0; k < 4; ++k) {
            float un  = uv[k] * fninc;
            int   iu  = (int)un;                 // trunc == floor (un >= 0)
            int   iuc = iu < ninc ? iu : (ninc - 1);
            float du  = un - (float)iuc;         // clamp trick: edge reproduces upper
            const float* row = rows + k * gcols;
            float g0 = row[iuc];
            float g1 = row[iuc + 1];             // adjacent -> ds_read2_b32 pair
            float h  = g1 - g0;                  // == inc bit-exactly
            xv[k] = g0 + h * du;
            pp *= h;                             // partial product over 4 dims
        }

        fvec4 o = {xv[0], xv[1], xv[2], xv[3]};
        x4[e] = o;                               // perfectly coalesced store

        // Combine the two half-point products: adjacent lanes hold one point.
        float po = __shfl_xor(pp, 1);
        if (is_even)
            lj_out[e >> 1] = __logf(pp * po) + lj_const;  // 32x4B contiguous/wave
    }
}

extern "C" void kernel_launch(void* const* d_in, const int* in_sizes, int n_in,
                              void* d_out, int out_size, void* d_ws, size_t ws_size,
                              hipStream_t stream) {
    const float* u    = (const float*)d_in[0];   // [N, 8]
    const float* grid = (const float*)d_in[1];   // [8, ninc+1]
    // d_in[2] = inc (recomputed as adjacent grid diffs), d_in[3] = ninc (derived)
    const int n     = in_sizes[0] / NDIM;
    const int gcols = in_sizes[1] / NDIM;        // ninc + 1
    const int ninc  = gcols - 1;
    const int nent  = 2 * n;                     // float4 half-point entries

    float* x_out  = (float*)d_out;
    float* lj_out = (float*)d_out + (size_t)n * NDIM;

    const float lj_const = (float)(NDIM * log((double)ninc));

    int blocks = (nent + TPB - 1) / TPB;
    if (blocks > 512) blocks = 512;              // 2 blocks/CU x 256 CUs = 32 waves/CU
    size_t lds_bytes = (size_t)NDIM * gcols * sizeof(float);

    vegas_map_kernel<<<blocks, TPB, lds_bytes, stream>>>(u, grid, x_out, lj_out,
                                                         nent, gcols, lj_const);
}